// Round 11
// baseline (31.820 us; speedup 1.0000x reference)
//
#include <hip/hip_runtime.h>

#define W 256
#define HTOT 1280            // num_img * H = 5 * 256
#define RR 8                 // output rows per wave
#define SPB (HTOT / RR)      // 160 stripes per batch
#define BS 64                // batch size
#define WPB 4                // waves per block (256 threads; 4 | 160 -> no batch straddle)
#define NWG ((BS * SPB) / WPB)  // 2560 blocks
#define BLKPB (SPB / WPB)    // 40 blocks per batch
#define NXCD 8
#define CPX (NWG / NXCD)     // 320 (2560 % 8 == 0 -> bijective swizzle)
#define NC (BLKPB * 3)       // 120 candidates per batch
#define NEG_FILL -1e9f

struct Cand { float v; int i; };

#define NINF_BITS ((int)0xFF800000)
#define IMAX 0x7fffffff

// ---------- DPP primitives (pure VALU, no DS) ----------
__device__ __forceinline__ float lane_up1(float x) {   // from lane-1, edge -> -inf
    return __int_as_float(__builtin_amdgcn_update_dpp(
        NINF_BITS, __float_as_int(x), 0x138, 0xF, 0xF, false));
}
__device__ __forceinline__ float lane_dn1(float x) {   // from lane+1, edge -> -inf
    return __int_as_float(__builtin_amdgcn_update_dpp(
        NINF_BITS, __float_as_int(x), 0x130, 0xF, 0xF, false));
}

template <int CTRL>
__device__ __forceinline__ float fmax_dpp(float x) {
    int s = __builtin_amdgcn_update_dpp(NINF_BITS, __float_as_int(x),
                                        CTRL, 0xF, 0xF, false);
    return fmaxf(x, __int_as_float(s));
}
template <int CTRL>
__device__ __forceinline__ int imin_dpp(int x) {
    int s = __builtin_amdgcn_update_dpp(IMAX, x, CTRL, 0xF, 0xF, false);
    return (s < x) ? s : x;
}

// wave64 max -> lane 63 (row_shr 1,2,4,8 then row_bcast15, row_bcast31)
__device__ __forceinline__ float wave_fmax_l63(float x) {
    x = fmax_dpp<0x111>(x); x = fmax_dpp<0x112>(x);
    x = fmax_dpp<0x114>(x); x = fmax_dpp<0x118>(x);
    x = fmax_dpp<0x142>(x); x = fmax_dpp<0x143>(x);
    return x;
}
__device__ __forceinline__ int wave_imin_l63(int x) {
    x = imin_dpp<0x111>(x); x = imin_dpp<0x112>(x);
    x = imin_dpp<0x114>(x); x = imin_dpp<0x118>(x);
    x = imin_dpp<0x142>(x); x = imin_dpp<0x143>(x);
    return x;
}

// Wave-wide top-3 from per-thread sorted lists (v0>=v1>=v2; within a thread
// v0 holds the smallest index among equals). Wave-uniform results, zero DS.
__device__ __forceinline__ void wave_top3(float v0, int i0, float v1, int i1,
                                          float v2, int i2,
                                          float outv[3], int outi[3]) {
    const float NINF = -__builtin_inff();
    #pragma unroll
    for (int k = 0; k < 3; ++k) {
        float m = __int_as_float(
            __builtin_amdgcn_readlane(__float_as_int(wave_fmax_l63(v0)), 63));
        int my = (v0 == m) ? i0 : IMAX;
        int widx = __builtin_amdgcn_readlane(wave_imin_l63(my), 63);
        outv[k] = m; outi[k] = widx;
        if (v0 == m && i0 == widx) {   // owner pops its head
            v0 = v1; i0 = i1; v1 = v2; i1 = i2; v2 = NINF; i2 = IMAX;
        }
    }
}

__device__ __forceinline__ bool better(float av, int ai, float bv, int bi) {
    return (av > bv) || (av == bv && ai < bi);
}

__device__ __forceinline__ void merge3(float cv, int ci,
                                       float& v0, int& i0,
                                       float& v1, int& i1,
                                       float& v2, int& i2) {
    if (better(cv, ci, v2, i2)) {
        if (better(cv, ci, v1, i1)) {
            v2 = v1; i2 = i1;
            if (better(cv, ci, v0, i0)) { v1 = v0; i1 = i0; v0 = cv; i0 = ci; }
            else { v1 = cv; i1 = ci; }
        } else { v2 = cv; i2 = ci; }
    }
}

// Four independent 64-lane waves per 256-thread block; each wave owns one
// 8-row stripe -> up to 32 waves/CU (HW cap) for latency hiding. No DS ops in
// the hot loop; halo via DPP; depth-4 float4 software pipeline. Tiny LDS merge
// at the end compresses 4 waves -> 3 candidates (keeps ws small).
// blockIdx is XCD-chunk swizzled so stripes sharing halo rows land on the
// same XCD's L2.
__global__ __launch_bounds__(64 * WPB) void peaks_phase1(const float* __restrict__ hm,
                                                         Cand* __restrict__ ws) {
    const int lane = threadIdx.x & 63;
    const int wv   = threadIdx.x >> 6;
    // bijective XCD-chunked swizzle (NWG % 8 == 0)
    const int lb = (blockIdx.x & (NXCD - 1)) * CPX + (blockIdx.x >> 3);
    const int g = lb * WPB + wv;           // stripe id
    const int b = g / SPB;                 // batch (wave-uniform)
    const int s = g - b * SPB;
    const int r0 = s * RR;
    const float NINF = -__builtin_inff();

    const float* base = hm + (size_t)b * (size_t)(HTOT * W) + lane * 4;

    auto LOADROW = [&](int gr) -> float4 {
        float4 v;
        if ((unsigned)gr < (unsigned)HTOT) {
            v = *(const float4*)(base + (size_t)gr * W);
        } else {
            v.x = NINF; v.y = NINF; v.z = NINF; v.w = NINF;
        }
        return v;
    };

    float h[5][4];
    float raw0[4], raw1[4], raw2[4];
    #pragma unroll
    for (int k = 0; k < 5; ++k) {
        h[k][0] = NINF; h[k][1] = NINF; h[k][2] = NINF; h[k][3] = NINF;
    }
    #pragma unroll
    for (int j = 0; j < 4; ++j) { raw0[j] = NINF; raw1[j] = NINF; raw2[j] = NINF; }

    float v0 = NINF, v1 = NINF, v2 = NINF;
    int   i0 = IMAX, i1 = IMAX, i2 = IMAX;

    // depth-4 software pipeline: 4 rows in flight
    float4 p0 = LOADROW(r0 - 2);
    float4 p1 = LOADROW(r0 - 1);
    float4 p2 = LOADROW(r0);
    float4 p3 = LOADROW(r0 + 1);

    #pragma unroll
    for (int r = 0; r < RR + 4; ++r) {
        float4 cur = p0;
        p0 = p1; p1 = p2; p2 = p3;
        if (r < RR) p3 = LOADROW(r0 + 2 + r);   // rows r0+2 .. r0+RR+1

        // halo via DPP (boundary lanes auto-fill -inf; full-W stripe so image
        // edge == wave edge)
        float L1 = lane_up1(cur.w);
        float L2 = lane_up1(cur.z);
        float R1 = lane_dn1(cur.x);
        float R2 = lane_dn1(cur.y);

        float myz   = fmaxf(cur.y, cur.z);
        float mxyz  = fmaxf(cur.x, myz);
        float myzw  = fmaxf(myz, cur.w);
        float mxyzw = fmaxf(mxyz, cur.w);
        float hm0 = fmaxf(fmaxf(L2, L1), mxyz);
        float hm1 = fmaxf(L1, mxyzw);
        float hm2 = fmaxf(mxyzw, R1);
        float hm3 = fmaxf(myzw, fmaxf(R1, R2));

        #pragma unroll
        for (int k = 0; k < 4; ++k) {
            h[k][0] = h[k + 1][0]; h[k][1] = h[k + 1][1];
            h[k][2] = h[k + 1][2]; h[k][3] = h[k + 1][3];
        }
        h[4][0] = hm0; h[4][1] = hm1; h[4][2] = hm2; h[4][3] = hm3;
        #pragma unroll
        for (int j = 0; j < 4; ++j) { raw0[j] = raw1[j]; raw1[j] = raw2[j]; }
        raw2[0] = cur.x; raw2[1] = cur.y; raw2[2] = cur.z; raw2[3] = cur.w;

        if (r >= 4) {
            const int rout = r0 + r - 4;
            #pragma unroll
            for (int j = 0; j < 4; ++j) {
                float rv = raw0[j];
                // cheap filter first: only compute window max when this value
                // could enter the top-3.
                if (rv > v2) {
                    float wmax = fmaxf(fmaxf(fmaxf(h[0][j], h[1][j]),
                                             fmaxf(h[2][j], h[3][j])), h[4][j]);
                    if (rv == wmax) {
                        int idx = rout * W + lane * 4 + j;
                        if (rv > v1) {
                            v2 = v1; i2 = i1;
                            if (rv > v0) { v1 = v0; i1 = i0; v0 = rv; i0 = idx; }
                            else         { v1 = rv; i1 = idx; }
                        } else { v2 = rv; i2 = idx; }
                    }
                }
            }
        }
    }

    // wave top-3 via DPP extraction (no DS)
    float outv[3]; int outi[3];
    wave_top3(v0, i0, v1, i1, v2, i2, outv, outi);

    // cross-wave merge inside the block (96 B LDS, one barrier)
    __shared__ float sv[WPB * 3];
    __shared__ int   si[WPB * 3];
    if (lane == 0) {
        sv[wv * 3 + 0] = outv[0]; sv[wv * 3 + 1] = outv[1]; sv[wv * 3 + 2] = outv[2];
        si[wv * 3 + 0] = outi[0]; si[wv * 3 + 1] = outi[1]; si[wv * 3 + 2] = outi[2];
    }
    __syncthreads();
    if (threadIdx.x == 0) {
        float b0 = sv[0], b1 = sv[1], b2 = sv[2];
        int   j0 = si[0], j1 = si[1], j2 = si[2];
        #pragma unroll
        for (int q = 3; q < WPB * 3; ++q) merge3(sv[q], si[q], b0, j0, b1, j1, b2, j2);
        Cand* o = ws + (size_t)lb * 3;    // logical id keeps batch grouping
        o[0].v = b0; o[0].i = j0;
        o[1].v = b1; o[1].i = j1;
        o[2].v = b2; o[2].i = j2;
    }
}

// One wave per batch: 120 candidates, 2 per lane, DPP extraction, no LDS.
__global__ __launch_bounds__(64) void peaks_phase2(const Cand* __restrict__ ws,
                                                   float* __restrict__ out) {
    const int b = blockIdx.x;
    const int t = threadIdx.x;
    const float NINF = -__builtin_inff();

    float v0 = NINF, v1 = NINF, v2 = NINF;
    int   i0 = IMAX, i1 = IMAX, i2 = IMAX;
    const Cand* src = ws + (size_t)b * NC;
    #pragma unroll
    for (int q = 0; q < 2; ++q) {
        int idx = q * 64 + t;           // coalesced; tail guarded (NC=120)
        if (idx < NC) {
            Cand e = src[idx];
            merge3(e.v, e.i, v0, i0, v1, i1, v2, i2);
        }
    }

    float outv[3]; int outi[3];
    wave_top3(v0, i0, v1, i1, v2, i2, outv, outi);

    if (t == 0) {
        // positions [64,3,3] at 0 ; scores [64,3] at 576 ; mask [64,3] at 768
        float* pos = out + (size_t)b * 9;
        float* sco = out + 576 + (size_t)b * 3;
        float* msk = out + 768 + (size_t)b * 3;
        #pragma unroll
        for (int k = 0; k < 3; ++k) {
            int idx = outi[k];
            pos[k * 3 + 0] = (float)(idx >> 16);
            pos[k * 3 + 1] = (float)((idx >> 8) & 255);
            pos[k * 3 + 2] = (float)(idx & 255);
            sco[k] = outv[k];
            msk[k] = (outv[k] > -1e30f) ? 1.0f : 0.0f;
        }
    }
}

extern "C" void kernel_launch(void* const* d_in, const int* in_sizes, int n_in,
                              void* d_out, int out_size, void* d_ws, size_t ws_size,
                              hipStream_t stream) {
    const float* hm = (const float*)d_in[0];
    float* out = (float*)d_out;
    Cand* ws = (Cand*)d_ws;  // 2560*3*8 = 61440 bytes

    peaks_phase1<<<NWG, 64 * WPB, 0, stream>>>(hm, ws);
    peaks_phase2<<<BS, 64, 0, stream>>>(ws, out);
}

// Round 12
// 28.930 us; speedup vs baseline: 1.0999x; 1.0999x over previous
//
#include <hip/hip_runtime.h>

#define W 256
#define HTOT 1280            // num_img * H = 5 * 256
#define RR 32                // output rows per wave
#define SPB (HTOT / RR)      // 40 stripes per batch
#define BS 64                // batch size
#define WPB 2                // independent waves per block (no barrier, no LDS)
#define NWG ((BS * SPB) / WPB)  // 1280 blocks
#define NXCD 8
#define CPX (NWG / NXCD)     // 160 (1280 % 8 == 0 -> bijective swizzle)
#define NC (SPB * 3)         // 120 candidates per batch
#define NEG_FILL -1e9f

struct Cand { float v; int i; };

#define NINF_BITS ((int)0xFF800000)
#define IMAX 0x7fffffff

// ---------- DPP primitives (pure VALU, no DS, no LDS) ----------
__device__ __forceinline__ float lane_up1(float x) {   // from lane-1, edge -> -inf
    return __int_as_float(__builtin_amdgcn_update_dpp(
        NINF_BITS, __float_as_int(x), 0x138, 0xF, 0xF, false));
}
__device__ __forceinline__ float lane_dn1(float x) {   // from lane+1, edge -> -inf
    return __int_as_float(__builtin_amdgcn_update_dpp(
        NINF_BITS, __float_as_int(x), 0x130, 0xF, 0xF, false));
}

template <int CTRL>
__device__ __forceinline__ float fmax_dpp(float x) {
    int s = __builtin_amdgcn_update_dpp(NINF_BITS, __float_as_int(x),
                                        CTRL, 0xF, 0xF, false);
    return fmaxf(x, __int_as_float(s));
}
template <int CTRL>
__device__ __forceinline__ int imin_dpp(int x) {
    int s = __builtin_amdgcn_update_dpp(IMAX, x, CTRL, 0xF, 0xF, false);
    return (s < x) ? s : x;
}

// wave64 max -> lane 63 (row_shr 1,2,4,8 then row_bcast15, row_bcast31)
__device__ __forceinline__ float wave_fmax_l63(float x) {
    x = fmax_dpp<0x111>(x); x = fmax_dpp<0x112>(x);
    x = fmax_dpp<0x114>(x); x = fmax_dpp<0x118>(x);
    x = fmax_dpp<0x142>(x); x = fmax_dpp<0x143>(x);
    return x;
}
__device__ __forceinline__ int wave_imin_l63(int x) {
    x = imin_dpp<0x111>(x); x = imin_dpp<0x112>(x);
    x = imin_dpp<0x114>(x); x = imin_dpp<0x118>(x);
    x = imin_dpp<0x142>(x); x = imin_dpp<0x143>(x);
    return x;
}

// Wave-wide top-3 from per-thread sorted lists (v0>=v1>=v2; within a thread
// v0 holds the smallest index among equals). Wave-uniform results, zero DS.
__device__ __forceinline__ void wave_top3(float v0, int i0, float v1, int i1,
                                          float v2, int i2,
                                          float outv[3], int outi[3]) {
    const float NINF = -__builtin_inff();
    #pragma unroll
    for (int k = 0; k < 3; ++k) {
        float m = __int_as_float(
            __builtin_amdgcn_readlane(__float_as_int(wave_fmax_l63(v0)), 63));
        int my = (v0 == m) ? i0 : IMAX;
        int widx = __builtin_amdgcn_readlane(wave_imin_l63(my), 63);
        outv[k] = m; outi[k] = widx;
        if (v0 == m && i0 == widx) {   // owner pops its head
            v0 = v1; i0 = i1; v1 = v2; i1 = i2; v2 = NINF; i2 = IMAX;
        }
    }
}

__device__ __forceinline__ bool better(float av, int ai, float bv, int bi) {
    return (av > bv) || (av == bv && ai < bi);
}

__device__ __forceinline__ void merge3(float cv, int ci,
                                       float& v0, int& i0,
                                       float& v1, int& i1,
                                       float& v2, int& i2) {
    if (better(cv, ci, v2, i2)) {
        if (better(cv, ci, v1, i1)) {
            v2 = v1; i2 = i1;
            if (better(cv, ci, v0, i0)) { v1 = v0; i1 = i0; v0 = cv; i0 = ci; }
            else { v1 = cv; i1 = ci; }
        } else { v2 = cv; i2 = ci; }
    }
}

// Two independent 64-lane waves per 128-thread block; each wave owns one
// 32-row stripe (halo over-read 1.125x vs 1.25x at RR=16). No LDS, no
// barriers, no DS ops. Thread owns 4 columns; halo via DPP; depth-4 float4
// software pipeline. blockIdx is XCD-chunk swizzled so stripes sharing halo
// rows land on the same XCD's L2.
__global__ __launch_bounds__(64 * WPB) void peaks_phase1(const float* __restrict__ hm,
                                                         Cand* __restrict__ ws) {
    const int lane = threadIdx.x & 63;
    const int wv   = threadIdx.x >> 6;
    // bijective XCD-chunked swizzle (NWG % 8 == 0)
    const int lb = (blockIdx.x & (NXCD - 1)) * CPX + (blockIdx.x >> 3);
    const int g = lb * WPB + wv;           // stripe id (2 | 40 -> no batch straddle)
    const int b = g / SPB;                 // batch (wave-uniform)
    const int s = g - b * SPB;
    const int r0 = s * RR;
    const float NINF = -__builtin_inff();

    const float* base = hm + (size_t)b * (size_t)(HTOT * W) + lane * 4;

    auto LOADROW = [&](int gr) -> float4 {
        float4 v;
        if ((unsigned)gr < (unsigned)HTOT) {
            v = *(const float4*)(base + (size_t)gr * W);
        } else {
            v.x = NINF; v.y = NINF; v.z = NINF; v.w = NINF;
        }
        return v;
    };

    float h[5][4];
    float raw0[4], raw1[4], raw2[4];
    #pragma unroll
    for (int k = 0; k < 5; ++k) {
        h[k][0] = NINF; h[k][1] = NINF; h[k][2] = NINF; h[k][3] = NINF;
    }
    #pragma unroll
    for (int j = 0; j < 4; ++j) { raw0[j] = NINF; raw1[j] = NINF; raw2[j] = NINF; }

    float v0 = NINF, v1 = NINF, v2 = NINF;
    int   i0 = IMAX, i1 = IMAX, i2 = IMAX;

    // depth-4 software pipeline: 4 rows in flight
    float4 p0 = LOADROW(r0 - 2);
    float4 p1 = LOADROW(r0 - 1);
    float4 p2 = LOADROW(r0);
    float4 p3 = LOADROW(r0 + 1);

    #pragma unroll
    for (int r = 0; r < RR + 4; ++r) {
        float4 cur = p0;
        p0 = p1; p1 = p2; p2 = p3;
        if (r < RR) p3 = LOADROW(r0 + 2 + r);   // rows r0+2 .. r0+RR+1

        // halo via DPP (boundary lanes auto-fill -inf; full-W stripe so image
        // edge == wave edge)
        float L1 = lane_up1(cur.w);
        float L2 = lane_up1(cur.z);
        float R1 = lane_dn1(cur.x);
        float R2 = lane_dn1(cur.y);

        float myz   = fmaxf(cur.y, cur.z);
        float mxyz  = fmaxf(cur.x, myz);
        float myzw  = fmaxf(myz, cur.w);
        float mxyzw = fmaxf(mxyz, cur.w);
        float hm0 = fmaxf(fmaxf(L2, L1), mxyz);
        float hm1 = fmaxf(L1, mxyzw);
        float hm2 = fmaxf(mxyzw, R1);
        float hm3 = fmaxf(myzw, fmaxf(R1, R2));

        #pragma unroll
        for (int k = 0; k < 4; ++k) {
            h[k][0] = h[k + 1][0]; h[k][1] = h[k + 1][1];
            h[k][2] = h[k + 1][2]; h[k][3] = h[k + 1][3];
        }
        h[4][0] = hm0; h[4][1] = hm1; h[4][2] = hm2; h[4][3] = hm3;
        #pragma unroll
        for (int j = 0; j < 4; ++j) { raw0[j] = raw1[j]; raw1[j] = raw2[j]; }
        raw2[0] = cur.x; raw2[1] = cur.y; raw2[2] = cur.z; raw2[3] = cur.w;

        if (r >= 4) {
            const int rout = r0 + r - 4;
            #pragma unroll
            for (int j = 0; j < 4; ++j) {
                float rv = raw0[j];
                // cheap filter first: only compute window max when this value
                // could enter the top-3.
                if (rv > v2) {
                    float wmax = fmaxf(fmaxf(fmaxf(h[0][j], h[1][j]),
                                             fmaxf(h[2][j], h[3][j])), h[4][j]);
                    if (rv == wmax) {
                        int idx = rout * W + lane * 4 + j;
                        if (rv > v1) {
                            v2 = v1; i2 = i1;
                            if (rv > v0) { v1 = v0; i1 = i0; v0 = rv; i0 = idx; }
                            else         { v1 = rv; i1 = idx; }
                        } else { v2 = rv; i2 = idx; }
                    }
                }
            }
        }
    }

    // wave top-3 via DPP extraction (no DS)
    float outv[3]; int outi[3];
    wave_top3(v0, i0, v1, i1, v2, i2, outv, outi);

    if (lane == 0) {
        Cand* o = ws + (size_t)g * 3;
        o[0].v = outv[0]; o[0].i = outi[0];
        o[1].v = outv[1]; o[1].i = outi[1];
        o[2].v = outv[2]; o[2].i = outi[2];
    }
}

// One wave per batch: 120 candidates, 2 per lane, DPP extraction, no LDS.
__global__ __launch_bounds__(64) void peaks_phase2(const Cand* __restrict__ ws,
                                                   float* __restrict__ out) {
    const int b = blockIdx.x;
    const int t = threadIdx.x;
    const float NINF = -__builtin_inff();

    float v0 = NINF, v1 = NINF, v2 = NINF;
    int   i0 = IMAX, i1 = IMAX, i2 = IMAX;
    const Cand* src = ws + (size_t)b * NC;
    #pragma unroll
    for (int q = 0; q < 2; ++q) {
        int idx = q * 64 + t;           // coalesced; tail guarded (NC=120)
        if (idx < NC) {
            Cand e = src[idx];
            merge3(e.v, e.i, v0, i0, v1, i1, v2, i2);
        }
    }

    float outv[3]; int outi[3];
    wave_top3(v0, i0, v1, i1, v2, i2, outv, outi);

    if (t == 0) {
        // positions [64,3,3] at 0 ; scores [64,3] at 576 ; mask [64,3] at 768
        float* pos = out + (size_t)b * 9;
        float* sco = out + 576 + (size_t)b * 3;
        float* msk = out + 768 + (size_t)b * 3;
        #pragma unroll
        for (int k = 0; k < 3; ++k) {
            int idx = outi[k];
            pos[k * 3 + 0] = (float)(idx >> 16);
            pos[k * 3 + 1] = (float)((idx >> 8) & 255);
            pos[k * 3 + 2] = (float)(idx & 255);
            sco[k] = outv[k];
            msk[k] = (outv[k] > -1e30f) ? 1.0f : 0.0f;
        }
    }
}

extern "C" void kernel_launch(void* const* d_in, const int* in_sizes, int n_in,
                              void* d_out, int out_size, void* d_ws, size_t ws_size,
                              hipStream_t stream) {
    const float* hm = (const float*)d_in[0];
    float* out = (float*)d_out;
    Cand* ws = (Cand*)d_ws;  // 2560*3*8 = 61440 bytes

    peaks_phase1<<<NWG, 64 * WPB, 0, stream>>>(hm, ws);
    peaks_phase2<<<BS, 64, 0, stream>>>(ws, out);
}